// Round 1
// baseline (4693.805 us; speedup 1.0000x reference)
//
#include <hip/hip_runtime.h>
#include <cstddef>

// Problem dims
#define B_  64
#define R_  49
#define F_  512
#define E_  512
#define H_  512
#define V_  10000
#define TT  32
#define TS  31   // T-1 decode steps

__device__ __forceinline__ float fsigm(float x) { return 1.0f / (1.0f + __expf(-x)); }
__device__ __forceinline__ float ftanh(float x) { return 1.0f - 2.0f / (__expf(2.0f * x) + 1.0f); }

// ---------------------------------------------------------------------------
// Generic fp32 NT GEMM: C[m,n] = sum_k A[m,k]*B[n,k] + bias1[n] + bias2[n]
// A: M x K (row stride lda), B: N x K (row stride ldb), C: M x N (row stride ldc)
// Tile 64x64, 256 threads, each thread 4x4. LDS staged [k][m] / [k][n].
// ---------------------------------------------------------------------------
__global__ __launch_bounds__(256) void gemm_nt_f32(
    const float* __restrict__ A, int lda,
    const float* __restrict__ Bm, int ldb,
    const float* __restrict__ bias1, const float* __restrict__ bias2,
    float* __restrict__ C, int ldc, int M, int N, int K)
{
    __shared__ __align__(16) float As[16][68];
    __shared__ __align__(16) float Bs[16][68];
    const int tid = threadIdx.x;
    const int m0 = blockIdx.y * 64, n0 = blockIdx.x * 64;
    const int tr = tid >> 4, tc = tid & 15;      // 16x16 thread grid
    const int lrow = tid >> 2, lk4 = (tid & 3) * 4;
    const bool am = (m0 + lrow) < M;
    const bool bn = (n0 + lrow) < N;
    const float* aptr = A + (size_t)(m0 + lrow) * lda + lk4;
    const float* bptr = Bm + (size_t)(n0 + lrow) * ldb + lk4;
    float acc[4][4] = {};

    for (int k0 = 0; k0 < K; k0 += 16) {
        float4 av = make_float4(0.f, 0.f, 0.f, 0.f);
        float4 bv = make_float4(0.f, 0.f, 0.f, 0.f);
        if (am) av = *(const float4*)(aptr + k0);
        if (bn) bv = *(const float4*)(bptr + k0);
        __syncthreads();
        As[lk4 + 0][lrow] = av.x; As[lk4 + 1][lrow] = av.y;
        As[lk4 + 2][lrow] = av.z; As[lk4 + 3][lrow] = av.w;
        Bs[lk4 + 0][lrow] = bv.x; Bs[lk4 + 1][lrow] = bv.y;
        Bs[lk4 + 2][lrow] = bv.z; Bs[lk4 + 3][lrow] = bv.w;
        __syncthreads();
#pragma unroll
        for (int kk = 0; kk < 16; ++kk) {
            float4 a = *(const float4*)&As[kk][tr * 4];
            float4 b = *(const float4*)&Bs[kk][tc * 4];
            acc[0][0] += a.x * b.x; acc[0][1] += a.x * b.y; acc[0][2] += a.x * b.z; acc[0][3] += a.x * b.w;
            acc[1][0] += a.y * b.x; acc[1][1] += a.y * b.y; acc[1][2] += a.y * b.z; acc[1][3] += a.y * b.w;
            acc[2][0] += a.z * b.x; acc[2][1] += a.z * b.y; acc[2][2] += a.z * b.z; acc[2][3] += a.z * b.w;
            acc[3][0] += a.w * b.x; acc[3][1] += a.w * b.y; acc[3][2] += a.w * b.z; acc[3][3] += a.w * b.w;
        }
    }
#pragma unroll
    for (int i = 0; i < 4; ++i) {
        int m = m0 + tr * 4 + i;
        if (m >= M) continue;
#pragma unroll
        for (int j = 0; j < 4; ++j) {
            int n = n0 + tc * 4 + j;
            if (n >= N) continue;
            float v = acc[i][j];
            if (bias1) v += bias1[n];
            if (bias2) v += bias2[n];
            C[(size_t)m * ldc + n] = v;
        }
    }
}

// ---------------------------------------------------------------------------
// avg[b,f] = mean_r features[b,r,f]
// ---------------------------------------------------------------------------
__global__ __launch_bounds__(256) void k_avg(const float* __restrict__ feat,
                                             float* __restrict__ avg)
{
    int id = blockIdx.x * 256 + threadIdx.x;   // 0 .. 64*512-1
    int b = id >> 9, f = id & 511;
    const float* p = feat + (size_t)b * R_ * F_ + f;
    float s = 0.f;
#pragma unroll 7
    for (int r = 0; r < R_; ++r) s += p[r * F_];
    avg[id] = s * (1.0f / 49.0f);
}

// ---------------------------------------------------------------------------
// Per-step attention: dec_att = h @ W_dec.T + b_dec;
// e = tanh(enc_att + dec_att) @ v_w + v_b; alpha = softmax(e);
// ctx[b,f] = sum_r alpha[r] * features[b,r,f].   One block per batch element.
// ---------------------------------------------------------------------------
__global__ __launch_bounds__(256) void k_att(
    const float* __restrict__ h_in, const float* __restrict__ enc_att,
    const float* __restrict__ feat, const float* __restrict__ W_dec,
    const float* __restrict__ b_dec, const float* __restrict__ v_w,
    const float* __restrict__ v_b, float* __restrict__ ctx)
{
    __shared__ float sh_h[512];
    __shared__ float sh_da[512];
    __shared__ float sh_e[49];
    __shared__ float sh_a[64];
    const int b = blockIdx.x, tid = threadIdx.x;

    for (int k = tid; k < 512; k += 256) sh_h[k] = h_in[b * 512 + k];
    __syncthreads();

    // dec_att
    for (int j = tid; j < 512; j += 256) {
        const float4* wr = (const float4*)(W_dec + (size_t)j * 512);
        float s = 0.f;
#pragma unroll 8
        for (int kq = 0; kq < 128; ++kq) {
            float4 w = wr[kq];
            s += w.x * sh_h[kq * 4 + 0] + w.y * sh_h[kq * 4 + 1]
               + w.z * sh_h[kq * 4 + 2] + w.w * sh_h[kq * 4 + 3];
        }
        sh_da[j] = s + b_dec[j];
    }
    __syncthreads();

    // e[r] — one region per wave, strided
    const int wave = tid >> 6, lane = tid & 63;
    for (int r = wave; r < R_; r += 4) {
        const float* er = enc_att + ((size_t)b * R_ + r) * 512;
        float s = 0.f;
        for (int h = lane; h < 512; h += 64)
            s += ftanh(er[h] + sh_da[h]) * v_w[h];
#pragma unroll
        for (int off = 32; off; off >>= 1) s += __shfl_down(s, off, 64);
        if (lane == 0) sh_e[r] = s + v_b[0];
    }
    __syncthreads();

    // softmax over 49 (wave 0)
    if (wave == 0) {
        float x = (lane < R_) ? sh_e[lane] : -1e30f;
        float mx = x;
#pragma unroll
        for (int off = 32; off; off >>= 1) mx = fmaxf(mx, __shfl_xor(mx, off, 64));
        float ex = (lane < R_) ? __expf(x - mx) : 0.f;
        float sm = ex;
#pragma unroll
        for (int off = 32; off; off >>= 1) sm += __shfl_xor(sm, off, 64);
        if (lane < R_) sh_a[lane] = ex / sm;
    }
    __syncthreads();

    // context
    for (int f = tid; f < 512; f += 256) {
        const float* fp = feat + (size_t)b * R_ * F_ + f;
        float s = 0.f;
#pragma unroll 7
        for (int r = 0; r < R_; ++r) s += sh_a[r] * fp[r * 512];
        ctx[b * 512 + f] = s;
    }
}

// ---------------------------------------------------------------------------
// Per-step LSTM: gates = ctx @ W_ih[:,E:].T + h @ W_hh.T + emb_gates[b,t,:]
// (emb_gates already holds word@W_ih[:, :E].T + b_ih + b_hh).
// Block = (b, quarter of hidden dim). 256 blocks.
// ---------------------------------------------------------------------------
__global__ __launch_bounds__(256) void k_lstm(
    const float* __restrict__ h_in, const float* __restrict__ c_in,
    const float* __restrict__ ctx, const float* __restrict__ emb_g,
    const float* __restrict__ W_ih, const float* __restrict__ W_hh,
    float* __restrict__ h_out, float* __restrict__ c_out,
    float* __restrict__ H_all, int t)
{
    __shared__ float sx[1024];   // [ctx | h]
    __shared__ float sg[512];    // 4 gates x 128
    const int b = blockIdx.x >> 2, jc = blockIdx.x & 3;
    const int tid = threadIdx.x;

    for (int k = tid; k < 512; k += 256) {
        sx[k] = ctx[b * 512 + k];
        sx[512 + k] = h_in[b * 512 + k];
    }
    __syncthreads();

#pragma unroll
    for (int pp = 0; pp < 2; ++pp) {
        int p = tid + pp * 256;          // 0..511
        int gate = p >> 7, jj = p & 127;
        int row = gate * 512 + jc * 128 + jj;
        const float4* wi = (const float4*)(W_ih + (size_t)row * 1024 + 512);
        const float4* wh = (const float4*)(W_hh + (size_t)row * 512);
        float s = emb_g[((size_t)b * TT + t) * 2048 + row];
#pragma unroll 4
        for (int kq = 0; kq < 128; ++kq) {
            float4 a = wi[kq];
            s += a.x * sx[kq * 4 + 0] + a.y * sx[kq * 4 + 1]
               + a.z * sx[kq * 4 + 2] + a.w * sx[kq * 4 + 3];
            float4 h4 = wh[kq];
            s += h4.x * sx[512 + kq * 4 + 0] + h4.y * sx[512 + kq * 4 + 1]
               + h4.z * sx[512 + kq * 4 + 2] + h4.w * sx[512 + kq * 4 + 3];
        }
        sg[p] = s;
    }
    __syncthreads();

    if (tid < 128) {
        int jj = tid;
        float ig = fsigm(sg[jj]);
        float fg = fsigm(sg[128 + jj]);
        float gg = ftanh(sg[256 + jj]);
        float og = fsigm(sg[384 + jj]);
        int j = jc * 128 + jj;
        float cn = fg * c_in[b * 512 + j] + ig * gg;
        float hn = og * ftanh(cn);
        c_out[b * 512 + j] = cn;
        h_out[b * 512 + j] = hn;
        H_all[((size_t)b * TS + t) * 512 + j] = hn;   // layout [b][t][h]
    }
}

// ---------------------------------------------------------------------------
extern "C" void kernel_launch(void* const* d_in, const int* in_sizes, int n_in,
                              void* d_out, int out_size, void* d_ws, size_t ws_size,
                              hipStream_t stream)
{
    (void)in_sizes; (void)n_in; (void)out_size; (void)ws_size;
    const float* feat     = (const float*)d_in[0];
    const float* caps     = (const float*)d_in[1];
    const float* W_enc    = (const float*)d_in[2];
    const float* b_enc    = (const float*)d_in[3];
    const float* W_dec    = (const float*)d_in[4];
    const float* b_dec    = (const float*)d_in[5];
    const float* v_w      = (const float*)d_in[6];
    const float* v_b      = (const float*)d_in[7];
    const float* W_ih     = (const float*)d_in[8];
    const float* W_hh     = (const float*)d_in[9];
    const float* b_ih     = (const float*)d_in[10];
    const float* b_hh     = (const float*)d_in[11];
    const float* W_init_h = (const float*)d_in[12];
    const float* b_init_h = (const float*)d_in[13];
    const float* W_init_c = (const float*)d_in[14];
    const float* b_init_c = (const float*)d_in[15];
    const float* W_out    = (const float*)d_in[16];
    const float* b_out    = (const float*)d_in[17];
    float* out = (float*)d_out;
    float* ws  = (float*)d_ws;

    // workspace layout (floats): ~28 MB total
    float* avg   = ws;                        // 64*512
    float* hbuf  = avg + 32768;               // 2 * 64*512 (ping-pong)
    float* cbuf  = hbuf + 65536;              // 2 * 64*512
    float* ctx   = cbuf + 65536;              // 64*512
    float* encat = ctx + 32768;               // 64*49*512
    float* embg  = encat + (size_t)B_ * R_ * H_;   // 64*32*2048
    float* Hall  = embg + (size_t)B_ * TT * 2048;  // 64*31*512

    dim3 thr(256);

    k_avg<<<128, thr, 0, stream>>>(feat, avg);
    // h0, c0
    gemm_nt_f32<<<dim3(8, 1), thr, 0, stream>>>(avg, 512, W_init_h, 512, b_init_h, nullptr,
                                                hbuf, 512, 64, 512, 512);
    gemm_nt_f32<<<dim3(8, 1), thr, 0, stream>>>(avg, 512, W_init_c, 512, b_init_c, nullptr,
                                                cbuf, 512, 64, 512, 512);
    // enc_att = features @ W_enc.T + b_enc   [3136, 512]
    gemm_nt_f32<<<dim3(8, 49), thr, 0, stream>>>(feat, 512, W_enc, 512, b_enc, nullptr,
                                                 encat, 512, 3136, 512, 512);
    // emb_gates = captions @ W_ih[:, :512].T + (b_ih + b_hh)   [2048, 2048]
    gemm_nt_f32<<<dim3(32, 32), thr, 0, stream>>>(caps, 512, W_ih, 1024, b_ih, b_hh,
                                                  embg, 2048, 2048, 2048, 512);

    // sequential decode
    for (int t = 0; t < TS; ++t) {
        const float* hc = hbuf + (t & 1) * 32768;
        const float* cc = cbuf + (t & 1) * 32768;
        float* hn = hbuf + ((t + 1) & 1) * 32768;
        float* cn = cbuf + ((t + 1) & 1) * 32768;
        k_att<<<64, thr, 0, stream>>>(hc, encat, feat, W_dec, b_dec, v_w, v_b, ctx);
        k_lstm<<<256, thr, 0, stream>>>(hc, cc, ctx, embg, W_ih, W_hh, hn, cn, Hall, t);
    }

    // logits = H_all @ W_out.T + b_out  -> d_out directly ([b][t][v] order)
    gemm_nt_f32<<<dim3(157, 31), thr, 0, stream>>>(Hall, 512, W_out, 512, b_out, nullptr,
                                                   out, 10000, 1984, 10000, 512);
}

// Round 2
// 4628.720 us; speedup vs baseline: 1.0141x; 1.0141x over previous
//
#include <hip/hip_runtime.h>
#include <hip/hip_cooperative_groups.h>
#include <cstddef>

namespace cg = cooperative_groups;

#define B_  64
#define R_  49
#define F_  512
#define H_  512
#define V_  10000
#define TT  32
#define TS  31

__device__ __forceinline__ float fsigm(float x) { return 1.0f / (1.0f + __expf(-x)); }
__device__ __forceinline__ float ftanh(float x) { return 1.0f - 2.0f / (__expf(2.0f * x) + 1.0f); }

// ---------------------------------------------------------------------------
// Generic fp32 NT GEMM (unchanged from round 1)
// ---------------------------------------------------------------------------
__global__ __launch_bounds__(256) void gemm_nt_f32(
    const float* __restrict__ A, int lda,
    const float* __restrict__ Bm, int ldb,
    const float* __restrict__ bias1, const float* __restrict__ bias2,
    float* __restrict__ C, int ldc, int M, int N, int K)
{
    __shared__ __align__(16) float As[16][68];
    __shared__ __align__(16) float Bs[16][68];
    const int tid = threadIdx.x;
    const int m0 = blockIdx.y * 64, n0 = blockIdx.x * 64;
    const int tr = tid >> 4, tc = tid & 15;
    const int lrow = tid >> 2, lk4 = (tid & 3) * 4;
    const bool am = (m0 + lrow) < M;
    const bool bn = (n0 + lrow) < N;
    const float* aptr = A + (size_t)(m0 + lrow) * lda + lk4;
    const float* bptr = Bm + (size_t)(n0 + lrow) * ldb + lk4;
    float acc[4][4] = {};

    for (int k0 = 0; k0 < K; k0 += 16) {
        float4 av = make_float4(0.f, 0.f, 0.f, 0.f);
        float4 bv = make_float4(0.f, 0.f, 0.f, 0.f);
        if (am) av = *(const float4*)(aptr + k0);
        if (bn) bv = *(const float4*)(bptr + k0);
        __syncthreads();
        As[lk4 + 0][lrow] = av.x; As[lk4 + 1][lrow] = av.y;
        As[lk4 + 2][lrow] = av.z; As[lk4 + 3][lrow] = av.w;
        Bs[lk4 + 0][lrow] = bv.x; Bs[lk4 + 1][lrow] = bv.y;
        Bs[lk4 + 2][lrow] = bv.z; Bs[lk4 + 3][lrow] = bv.w;
        __syncthreads();
#pragma unroll
        for (int kk = 0; kk < 16; ++kk) {
            float4 a = *(const float4*)&As[kk][tr * 4];
            float4 b = *(const float4*)&Bs[kk][tc * 4];
            acc[0][0] += a.x * b.x; acc[0][1] += a.x * b.y; acc[0][2] += a.x * b.z; acc[0][3] += a.x * b.w;
            acc[1][0] += a.y * b.x; acc[1][1] += a.y * b.y; acc[1][2] += a.y * b.z; acc[1][3] += a.y * b.w;
            acc[2][0] += a.z * b.x; acc[2][1] += a.z * b.y; acc[2][2] += a.z * b.z; acc[2][3] += a.z * b.w;
            acc[3][0] += a.w * b.x; acc[3][1] += a.w * b.y; acc[3][2] += a.w * b.z; acc[3][3] += a.w * b.w;
        }
    }
#pragma unroll
    for (int i = 0; i < 4; ++i) {
        int m = m0 + tr * 4 + i;
        if (m >= M) continue;
#pragma unroll
        for (int j = 0; j < 4; ++j) {
            int n = n0 + tc * 4 + j;
            if (n >= N) continue;
            float v = acc[i][j];
            if (bias1) v += bias1[n];
            if (bias2) v += bias2[n];
            C[(size_t)m * ldc + n] = v;
        }
    }
}

__global__ __launch_bounds__(256) void k_avg(const float* __restrict__ feat,
                                             float* __restrict__ avg)
{
    int id = blockIdx.x * 256 + threadIdx.x;
    int b = id >> 9, f = id & 511;
    const float* p = feat + (size_t)b * R_ * F_ + f;
    float s = 0.f;
#pragma unroll 7
    for (int r = 0; r < R_; ++r) s += p[r * F_];
    avg[id] = s * (1.0f / 49.0f);
}

// ---------------------------------------------------------------------------
// Persistent cooperative decode: all 31 steps in one launch.
// Grid = 256 blocks x 256 threads (1 block/CU guaranteed co-resident).
// Per step: [A] dec_att (j-parallel, 2 rows/block)  -> grid.sync
//           [B] e/softmax/ctx (b-parallel, 64 blocks) -> grid.sync
//           [C] gates+pointwise (2 hidden idx/block, lane=batch) -> grid.sync
// c-state lives in a VGPR across all steps.
// ---------------------------------------------------------------------------
__global__ __launch_bounds__(256, 1) void decode_coop(
    const float* __restrict__ feat,  const float* __restrict__ encat,
    const float* __restrict__ W_dec, const float* __restrict__ b_dec,
    const float* __restrict__ v_w,   const float* __restrict__ v_b,
    const float* __restrict__ W_ih,  const float* __restrict__ W_hh,
    const float* __restrict__ embg,  const float* __restrict__ cbuf,
    float* __restrict__ hbuf, float* __restrict__ dec_att,
    float* __restrict__ ctx,  float* __restrict__ Hall)
{
    cg::grid_group grid = cg::this_grid();
    __shared__ __align__(16) float4 xT4[64 * 65];   // 256-k tile, transposed, padded
    __shared__ float red[4][8][64];                  // cross-wave reduce
    __shared__ float da_sh[512];
    __shared__ float e_sh[49];
    __shared__ float a_sh[49];

    const int tid  = threadIdx.x;
    const int bid  = blockIdx.x;
    const int lane = tid & 63;
    const int wvu  = __builtin_amdgcn_readfirstlane(tid >> 6);

    // persistent cell state for this block's 2 hidden indices (threads 0..127)
    float creg = 0.f;
    if (tid < 128) creg = cbuf[(size_t)(tid & 63) * 512 + 2 * bid + (tid >> 6)];

    // stage 256-k slab of a [64][512] row-major src (offset pre-applied) into
    // xT4[k4][b] (float4 per k4), 65-slot padded rows -> conflict-free reads.
    const int sb = tid >> 2, sc = tid & 3;
    auto stage256 = [&](const float* src) {
        const float* srow = src + (size_t)sb * 512;
#pragma unroll
        for (int i = 0; i < 16; ++i) {
            int k4 = sc + 4 * i;
            xT4[k4 * 65 + sb] = *(const float4*)(srow + k4 * 4);
        }
    };

    for (int t = 0; t < TS; ++t) {
        const float* hcur = hbuf + (size_t)(t & 1) * (B_ * H_);
        float* hnew = hbuf + (size_t)((t + 1) & 1) * (B_ * H_);

        // ---------------- phase A: dec_att[b][2*bid + r] ----------------
        float accA[2] = {0.f, 0.f};
        for (int tile = 0; tile < 2; ++tile) {
            __syncthreads();
            stage256(hcur + tile * 256);
            __syncthreads();
            const float* w0 = W_dec + (size_t)(2 * bid) * 512 + tile * 256 + wvu * 64;
#pragma unroll 4
            for (int kk = 0; kk < 16; ++kk) {
                float4 xv = xT4[(wvu * 16 + kk) * 65 + lane];
                float4 wa = *(const float4*)(w0 + kk * 4);
                float4 wb = *(const float4*)(w0 + 512 + kk * 4);
                accA[0] += wa.x * xv.x + wa.y * xv.y + wa.z * xv.z + wa.w * xv.w;
                accA[1] += wb.x * xv.x + wb.y * xv.y + wb.z * xv.z + wb.w * xv.w;
            }
        }
        red[tid >> 6][0][lane] = accA[0];
        red[tid >> 6][1][lane] = accA[1];
        __syncthreads();
        if (tid < 128) {
            int r = tid >> 6, b = tid & 63;
            float s = red[0][r][b] + red[1][r][b] + red[2][r][b] + red[3][r][b];
            dec_att[(size_t)b * 512 + 2 * bid + r] = s + b_dec[2 * bid + r];
        }
        grid.sync();

        // ---------------- phase B: e, softmax, ctx (blocks 0..63) -------
        if (bid < 64) {
            const int b = bid;
            for (int k = tid; k < 512; k += 256) da_sh[k] = dec_att[(size_t)b * 512 + k];
            __syncthreads();
            for (int r = wvu; r < R_; r += 4) {
                const float* er = encat + ((size_t)b * R_ + r) * 512;
                float s = 0.f;
#pragma unroll 8
                for (int i = 0; i < 8; ++i) {
                    int j = i * 64 + lane;
                    s += ftanh(er[j] + da_sh[j]) * v_w[j];
                }
#pragma unroll
                for (int off = 32; off; off >>= 1) s += __shfl_down(s, off, 64);
                if (lane == 0) e_sh[r] = s + v_b[0];
            }
            __syncthreads();
            if (tid < 64) {
                float x = (lane < R_) ? e_sh[lane] : -1e30f;
                float mx = x;
#pragma unroll
                for (int off = 32; off; off >>= 1) mx = fmaxf(mx, __shfl_xor(mx, off, 64));
                float ex = (lane < R_) ? __expf(x - mx) : 0.f;
                float sm = ex;
#pragma unroll
                for (int off = 32; off; off >>= 1) sm += __shfl_xor(sm, off, 64);
                if (lane < R_) a_sh[lane] = ex / sm;
            }
            __syncthreads();
            for (int f = tid; f < 512; f += 256) {
                const float* fp = feat + (size_t)b * R_ * F_ + f;
                float s = 0.f;
#pragma unroll 7
                for (int r = 0; r < R_; ++r) s += a_sh[r] * fp[r * 512];
                ctx[(size_t)b * 512 + f] = s;
            }
        }
        grid.sync();

        // ---------------- phase C: gates + LSTM pointwise ---------------
        // rows: gate g, hidden j = 2*bid + jj  (g=0..3, jj=0..1)
        float acc[8] = {0.f, 0.f, 0.f, 0.f, 0.f, 0.f, 0.f, 0.f};
        for (int tile = 0; tile < 4; ++tile) {
            __syncthreads();
            stage256((tile < 2 ? ctx : hcur) + (tile & 1) * 256);
            __syncthreads();
            const float* wbase;
            int rstride;
            if (tile < 2) { wbase = W_ih + 512 + tile * 256 + wvu * 64; rstride = 1024; }
            else          { wbase = W_hh + (tile - 2) * 256 + wvu * 64; rstride = 512; }
            const float* wrow = wbase + (size_t)(2 * bid) * rstride;
#pragma unroll 2
            for (int kk = 0; kk < 16; ++kk) {
                float4 xv = xT4[(wvu * 16 + kk) * 65 + lane];
#pragma unroll
                for (int g = 0; g < 4; ++g) {
                    const float* wg = wrow + (size_t)(g * 512) * rstride;
                    float4 w0 = *(const float4*)(wg + kk * 4);
                    float4 w1 = *(const float4*)(wg + rstride + kk * 4);
                    acc[g * 2 + 0] += w0.x * xv.x + w0.y * xv.y + w0.z * xv.z + w0.w * xv.w;
                    acc[g * 2 + 1] += w1.x * xv.x + w1.y * xv.y + w1.z * xv.z + w1.w * xv.w;
                }
            }
        }
        __syncthreads();
#pragma unroll
        for (int rr = 0; rr < 8; ++rr) red[tid >> 6][rr][lane] = acc[rr];
        __syncthreads();
        if (tid < 128) {
            int pjj = tid >> 6, b = tid & 63;
            int j = 2 * bid + pjj;
            float gv[4];
#pragma unroll
            for (int g = 0; g < 4; ++g) {
                int rr = g * 2 + pjj;
                float s = red[0][rr][b] + red[1][rr][b] + red[2][rr][b] + red[3][rr][b];
                gv[g] = s + embg[((size_t)b * TT + t) * 2048 + g * 512 + j];
            }
            float ig = fsigm(gv[0]), fg = fsigm(gv[1]);
            float gg = ftanh(gv[2]), og = fsigm(gv[3]);
            creg = fg * creg + ig * gg;
            float hn = og * ftanh(creg);
            hnew[(size_t)b * 512 + j] = hn;
            Hall[((size_t)b * TS + t) * 512 + j] = hn;
        }
        grid.sync();
    }
}

// ---------------------------------------------------------------------------
extern "C" void kernel_launch(void* const* d_in, const int* in_sizes, int n_in,
                              void* d_out, int out_size, void* d_ws, size_t ws_size,
                              hipStream_t stream)
{
    (void)in_sizes; (void)n_in; (void)out_size; (void)ws_size;
    const float* feat     = (const float*)d_in[0];
    const float* caps     = (const float*)d_in[1];
    const float* W_enc    = (const float*)d_in[2];
    const float* b_enc    = (const float*)d_in[3];
    const float* W_dec    = (const float*)d_in[4];
    const float* b_dec    = (const float*)d_in[5];
    const float* v_w      = (const float*)d_in[6];
    const float* v_b      = (const float*)d_in[7];
    const float* W_ih     = (const float*)d_in[8];
    const float* W_hh     = (const float*)d_in[9];
    const float* b_ih     = (const float*)d_in[10];
    const float* b_hh     = (const float*)d_in[11];
    const float* W_init_h = (const float*)d_in[12];
    const float* b_init_h = (const float*)d_in[13];
    const float* W_init_c = (const float*)d_in[14];
    const float* b_init_c = (const float*)d_in[15];
    const float* W_out    = (const float*)d_in[16];
    const float* b_out    = (const float*)d_in[17];
    float* out = (float*)d_out;
    float* ws  = (float*)d_ws;

    // workspace layout (floats), ~26.8 MiB
    float* avg    = ws;                                   // 32768
    float* hbuf   = avg + 32768;                          // 2 * 32768 (ping-pong)
    float* cbuf   = hbuf + 65536;                         // 32768
    float* ctx    = cbuf + 32768;                         // 32768
    float* datt   = ctx + 32768;                          // 32768
    float* encat  = datt + 32768;                         // 64*49*512
    float* embg   = encat + (size_t)B_ * R_ * H_;         // 64*32*2048
    float* Hall   = embg + (size_t)B_ * TT * 2048;        // 64*31*512

    dim3 thr(256);

    k_avg<<<128, thr, 0, stream>>>(feat, avg);
    gemm_nt_f32<<<dim3(8, 1), thr, 0, stream>>>(avg, 512, W_init_h, 512, b_init_h, nullptr,
                                                hbuf, 512, 64, 512, 512);
    gemm_nt_f32<<<dim3(8, 1), thr, 0, stream>>>(avg, 512, W_init_c, 512, b_init_c, nullptr,
                                                cbuf, 512, 64, 512, 512);
    gemm_nt_f32<<<dim3(8, 49), thr, 0, stream>>>(feat, 512, W_enc, 512, b_enc, nullptr,
                                                 encat, 512, 3136, 512, 512);
    gemm_nt_f32<<<dim3(32, 32), thr, 0, stream>>>(caps, 512, W_ih, 1024, b_ih, b_hh,
                                                  embg, 2048, 2048, 2048, 512);

    // persistent cooperative decode (all 31 steps)
    {
        const float* a0 = feat;   const float* a1 = encat;
        const float* a2 = W_dec;  const float* a3 = b_dec;
        const float* a4 = v_w;    const float* a5 = v_b;
        const float* a6 = W_ih;   const float* a7 = W_hh;
        const float* a8 = embg;   const float* a9 = cbuf;
        float* a10 = hbuf; float* a11 = datt; float* a12 = ctx; float* a13 = Hall;
        void* args[] = { &a0, &a1, &a2, &a3, &a4, &a5, &a6, &a7,
                         &a8, &a9, &a10, &a11, &a12, &a13 };
        hipLaunchCooperativeKernel((const void*)decode_coop, dim3(256), dim3(256),
                                   args, 0, stream);
    }

    // logits = H_all @ W_out.T + b_out
    gemm_nt_f32<<<dim3(157, 31), thr, 0, stream>>>(Hall, 512, W_out, 512, b_out, nullptr,
                                                   out, 10000, 1984, 10000, 512);
}